// Round 2
// 729.973 us; speedup vs baseline: 1.0216x; 1.0216x over previous
//
#include <hip/hip_runtime.h>
#include <cstddef>

// TwinSAGE: 2-layer GraphSAGE (mean aggr) + twin query path + 2-way layer
// attention + output projection.
// Round 5: identical to round 4 (infra retry). Dispatch-count 27->11
// (fused CSR build, fused wtrans, fused GEMM pairs); unified 128x256-block
// GEMM (A read+converted once, reg prefetch of next k-tile); agg 8-deep.

namespace {

constexpr int N1i  = 100000;
constexpr int Bni  = 10000;
constexpr int E0i  = 1000000;
constexpr int E1i  = 100000;
constexpr int FIN  = 128;
constexpr int HID  = 256;
constexpr int NCLS = 40;

typedef __attribute__((ext_vector_type(8))) short short8;
typedef __attribute__((ext_vector_type(8))) unsigned short ushort8;
typedef __attribute__((ext_vector_type(4))) float floatx4;

// ---------------- fused CSR build ----------------

__global__ void hist_both_kernel(const int* __restrict__ dst0, const int* __restrict__ dst1,
                                 int* __restrict__ cnt0, int* __restrict__ cnt1) {
    int i = blockIdx.x * blockDim.x + threadIdx.x;
    if (i < E0i) atomicAdd(&cnt0[dst0[i]], 1);
    else if (i < E0i + E1i) atomicAdd(&cnt1[dst1[i - E0i]], 1);
}

__global__ void partial_sum_both_kernel(const int* __restrict__ cnt0, const int* __restrict__ cnt1,
                                        int* __restrict__ bsum0, int* __restrict__ bsum1, int nb0) {
    __shared__ int s[256];
    const int* cnt; int n; int* bsum; int bi;
    if ((int)blockIdx.x < nb0) { cnt = cnt0; n = N1i; bsum = bsum0; bi = blockIdx.x; }
    else                       { cnt = cnt1; n = Bni; bsum = bsum1; bi = blockIdx.x - nb0; }
    int i = bi * 256 + threadIdx.x;
    s[threadIdx.x] = (i < n) ? cnt[i] : 0;
    __syncthreads();
    for (int o = 128; o > 0; o >>= 1) {
        if (threadIdx.x < o) s[threadIdx.x] += s[threadIdx.x + o];
        __syncthreads();
    }
    if (threadIdx.x == 0) bsum[bi] = s[0];
}

// grid = 2 blocks, 512 threads: block 0 scans bsum0, block 1 scans bsum1.
__global__ void scan_bsum_both_kernel(int* __restrict__ bsum0, int nb0, int* __restrict__ tot0,
                                      int* __restrict__ bsum1, int nb1, int* __restrict__ tot1) {
    __shared__ int s[512];
    int* bsum; int nb; int* tot;
    if (blockIdx.x == 0) { bsum = bsum0; nb = nb0; tot = tot0; }
    else                 { bsum = bsum1; nb = nb1; tot = tot1; }
    int t = threadIdx.x;
    int v = (t < nb) ? bsum[t] : 0;
    s[t] = v;
    __syncthreads();
    for (int o = 1; o < 512; o <<= 1) {
        int u = (t >= o) ? s[t - o] : 0;
        __syncthreads();
        s[t] += u;
        __syncthreads();
    }
    if (t < nb) bsum[t] = s[t] - v;   // exclusive
    if (t == 511) *tot = s[511];
}

// Writes rp[i] (exclusive prefix) AND resets cnt[i] to the same value so
// cnt doubles as the scatter cursor (replaces the old copy kernel).
__global__ void scan_final_both_kernel(int* __restrict__ cnt0, const int* __restrict__ bsum0, int* __restrict__ rp0,
                                       int* __restrict__ cnt1, const int* __restrict__ bsum1, int* __restrict__ rp1,
                                       int nb0) {
    __shared__ int s[256];
    int* cnt; const int* bsum; int* rp; int n; int bi;
    if ((int)blockIdx.x < nb0) { cnt = cnt0; bsum = bsum0; rp = rp0; n = N1i; bi = blockIdx.x; }
    else                       { cnt = cnt1; bsum = bsum1; rp = rp1; n = Bni; bi = blockIdx.x - nb0; }
    int t = threadIdx.x;
    int i = bi * 256 + t;
    int v = (i < n) ? cnt[i] : 0;
    s[t] = v;
    __syncthreads();
    for (int o = 1; o < 256; o <<= 1) {
        int u = (t >= o) ? s[t - o] : 0;
        __syncthreads();
        s[t] += u;
        __syncthreads();
    }
    if (i < n) {
        int r = bsum[bi] + s[t] - v;  // exclusive
        rp[i]  = r;
        cnt[i] = r;                   // cursor for scatter
    }
}

__global__ void scatter_both_kernel(const int* __restrict__ src0, const int* __restrict__ dst0,
                                    const int* __restrict__ src1, const int* __restrict__ dst1,
                                    int* __restrict__ cur0, int* __restrict__ cur1,
                                    int* __restrict__ es0, int* __restrict__ es1) {
    int i = blockIdx.x * blockDim.x + threadIdx.x;
    if (i < E0i) {
        int p = atomicAdd(&cur0[dst0[i]], 1);
        es0[p] = src0[i];
    } else if (i < E0i + E1i) {
        int j = i - E0i;
        int p = atomicAdd(&cur1[dst1[j]], 1);
        es1[p] = src1[j];
    }
}

// ---------------- Mean aggregation (one wave per target, 8-deep MLP) ----

__global__ __launch_bounds__(256) void agg_mean128_kernel(
    const float* __restrict__ x, const int* __restrict__ rp,
    const int* __restrict__ es, float* __restrict__ out, int ntgt) {
    int tgt  = blockIdx.x * 4 + (threadIdx.x >> 6);
    int lane = threadIdx.x & 63;
    if (tgt >= ntgt) return;
    int b = rp[tgt], e = rp[tgt + 1];
    int d = e - b;
    float ax = 0.f, ay = 0.f;
    const float* xp = x + lane * 2;
    for (int base = 0; base < d; base += 64) {
        int rem = d - base; if (rem > 64) rem = 64;
        int li  = lane < rem ? lane : rem - 1;
        int idx = es[b + base + li];            // one coalesced load / 64 edges
        int j = 0;
        for (; j + 8 <= rem; j += 8) {
            int i0 = __shfl(idx, j + 0), i1 = __shfl(idx, j + 1);
            int i2 = __shfl(idx, j + 2), i3 = __shfl(idx, j + 3);
            int i4 = __shfl(idx, j + 4), i5 = __shfl(idx, j + 5);
            int i6 = __shfl(idx, j + 6), i7 = __shfl(idx, j + 7);
            float2 v0 = *(const float2*)(xp + (size_t)i0 * FIN);
            float2 v1 = *(const float2*)(xp + (size_t)i1 * FIN);
            float2 v2 = *(const float2*)(xp + (size_t)i2 * FIN);
            float2 v3 = *(const float2*)(xp + (size_t)i3 * FIN);
            float2 v4 = *(const float2*)(xp + (size_t)i4 * FIN);
            float2 v5 = *(const float2*)(xp + (size_t)i5 * FIN);
            float2 v6 = *(const float2*)(xp + (size_t)i6 * FIN);
            float2 v7 = *(const float2*)(xp + (size_t)i7 * FIN);
            ax += v0.x + v1.x + v2.x + v3.x + v4.x + v5.x + v6.x + v7.x;
            ay += v0.y + v1.y + v2.y + v3.y + v4.y + v5.y + v6.y + v7.y;
        }
        for (; j + 4 <= rem; j += 4) {
            int i0 = __shfl(idx, j + 0), i1 = __shfl(idx, j + 1);
            int i2 = __shfl(idx, j + 2), i3 = __shfl(idx, j + 3);
            float2 v0 = *(const float2*)(xp + (size_t)i0 * FIN);
            float2 v1 = *(const float2*)(xp + (size_t)i1 * FIN);
            float2 v2 = *(const float2*)(xp + (size_t)i2 * FIN);
            float2 v3 = *(const float2*)(xp + (size_t)i3 * FIN);
            ax += v0.x + v1.x + v2.x + v3.x;
            ay += v0.y + v1.y + v2.y + v3.y;
        }
        for (; j < rem; j++) {
            int i0 = __shfl(idx, j);
            float2 v0 = *(const float2*)(xp + (size_t)i0 * FIN);
            ax += v0.x; ay += v0.y;
        }
    }
    float inv = 1.0f / fmaxf((float)d, 1.0f);
    float2 r; r.x = ax * inv; r.y = ay * inv;
    *(float2*)(out + (size_t)tgt * FIN + lane * 2) = r;
}

__global__ __launch_bounds__(256) void agg_mean256_kernel(
    const float* __restrict__ h, const int* __restrict__ rp,
    const int* __restrict__ es, float* __restrict__ out, int ntgt) {
    int tgt  = blockIdx.x * 4 + (threadIdx.x >> 6);
    int lane = threadIdx.x & 63;
    if (tgt >= ntgt) return;
    int b = rp[tgt], e = rp[tgt + 1];
    int d = e - b;
    float4 acc = {0.f, 0.f, 0.f, 0.f};
    const float* hp = h + lane * 4;
    for (int base = 0; base < d; base += 64) {
        int rem = d - base; if (rem > 64) rem = 64;
        int li  = lane < rem ? lane : rem - 1;
        int idx = es[b + base + li];
        int j = 0;
        for (; j + 8 <= rem; j += 8) {
            int i0 = __shfl(idx, j + 0), i1 = __shfl(idx, j + 1);
            int i2 = __shfl(idx, j + 2), i3 = __shfl(idx, j + 3);
            int i4 = __shfl(idx, j + 4), i5 = __shfl(idx, j + 5);
            int i6 = __shfl(idx, j + 6), i7 = __shfl(idx, j + 7);
            float4 v0 = *(const float4*)(hp + (size_t)i0 * HID);
            float4 v1 = *(const float4*)(hp + (size_t)i1 * HID);
            float4 v2 = *(const float4*)(hp + (size_t)i2 * HID);
            float4 v3 = *(const float4*)(hp + (size_t)i3 * HID);
            float4 v4 = *(const float4*)(hp + (size_t)i4 * HID);
            float4 v5 = *(const float4*)(hp + (size_t)i5 * HID);
            float4 v6 = *(const float4*)(hp + (size_t)i6 * HID);
            float4 v7 = *(const float4*)(hp + (size_t)i7 * HID);
            acc.x += v0.x + v1.x + v2.x + v3.x + v4.x + v5.x + v6.x + v7.x;
            acc.y += v0.y + v1.y + v2.y + v3.y + v4.y + v5.y + v6.y + v7.y;
            acc.z += v0.z + v1.z + v2.z + v3.z + v4.z + v5.z + v6.z + v7.z;
            acc.w += v0.w + v1.w + v2.w + v3.w + v4.w + v5.w + v6.w + v7.w;
        }
        for (; j + 4 <= rem; j += 4) {
            int i0 = __shfl(idx, j + 0), i1 = __shfl(idx, j + 1);
            int i2 = __shfl(idx, j + 2), i3 = __shfl(idx, j + 3);
            float4 v0 = *(const float4*)(hp + (size_t)i0 * HID);
            float4 v1 = *(const float4*)(hp + (size_t)i1 * HID);
            float4 v2 = *(const float4*)(hp + (size_t)i2 * HID);
            float4 v3 = *(const float4*)(hp + (size_t)i3 * HID);
            acc.x += v0.x + v1.x + v2.x + v3.x;
            acc.y += v0.y + v1.y + v2.y + v3.y;
            acc.z += v0.z + v1.z + v2.z + v3.z;
            acc.w += v0.w + v1.w + v2.w + v3.w;
        }
        for (; j < rem; j++) {
            int i0 = __shfl(idx, j);
            float4 v0 = *(const float4*)(hp + (size_t)i0 * HID);
            acc.x += v0.x; acc.y += v0.y; acc.z += v0.z; acc.w += v0.w;
        }
    }
    float inv = 1.0f / fmaxf((float)d, 1.0f);
    float4 r; r.x = acc.x * inv; r.y = acc.y * inv; r.z = acc.z * inv; r.w = acc.w * inv;
    *(float4*)(out + (size_t)tgt * HID + lane * 4) = r;
}

// ---------------- weight transpose + bf16 hi/lo split (fused x4) --------

__device__ inline unsigned short bf16_rne_u(unsigned u) {
    unsigned r = u + 0x7fffu + ((u >> 16) & 1u);
    return (unsigned short)(r >> 16);
}

__global__ void wtrans_all_kernel(const float* __restrict__ W1l, const float* __restrict__ W1r,
                                  const float* __restrict__ W2l, const float* __restrict__ W2r,
                                  unsigned short* __restrict__ w1lh, unsigned short* __restrict__ w1ll,
                                  unsigned short* __restrict__ w1rh, unsigned short* __restrict__ w1rl,
                                  unsigned short* __restrict__ w2lh, unsigned short* __restrict__ w2ll,
                                  unsigned short* __restrict__ w2rh, unsigned short* __restrict__ w2rl) {
    int e = blockIdx.x * 256 + threadIdx.x;
    const float* W; unsigned short* hiT; unsigned short* loT; int K; int idx;
    if (e < 65536) {
        K = 128;
        if (e < 32768) { W = W1l; hiT = w1lh; loT = w1ll; idx = e; }
        else           { W = W1r; hiT = w1rh; loT = w1rl; idx = e - 32768; }
    } else {
        K = 256;
        int e2 = e - 65536;
        if (e2 < 65536) { W = W2l; hiT = w2lh; loT = w2ll; idx = e2; }
        else            { W = W2r; hiT = w2rh; loT = w2rl; idx = e2 - 65536; }
    }
    int k = idx >> 8, n = idx & 255;
    float f = W[idx];
    unsigned short hs = bf16_rne_u(__float_as_uint(f));
    float lo = f - __uint_as_float((unsigned)hs << 16);
    unsigned short ls = bf16_rne_u(__float_as_uint(lo));
    hiT[n * K + k] = hs;
    loT[n * K + k] = ls;
}

// ---------------- unified split-bf16 MFMA GEMM ----------------
// C[M x 256] = relu(A1@B1 + A2@B2 + bias), A fp32 row-major (stride = K),
// B pre-split/transposed bf16 hi/lo [256][K].
// 3-term split: Ahi*Bhi + Ahi*Blo + Alo*Bhi (error ~2^-17 rel).
// Block 128x256 (single N-block: A read+converted ONCE), 8 waves,
// wave = 4x4 tiles of mfma_f32_16x16x32_bf16, BK=32, reg prefetch of
// next k-tile issued before the MFMA phase. Two jobs per launch
// (blockIdx ranges) to fuse the small twin-path GEMMs.

__device__ inline void cvt_store8(unsigned short* hi_dst, unsigned short* lo_dst,
                                  const float* v) {
    ushort8 hv, lv;
#pragma unroll
    for (int i = 0; i < 8; i++) {
        float f = v[i];
        unsigned short hs = bf16_rne_u(__float_as_uint(f));
        float lo = f - __uint_as_float((unsigned)hs << 16);
        hv[i] = hs;
        lv[i] = bf16_rne_u(__float_as_uint(lo));
    }
    *(ushort8*)hi_dst = hv;
    *(ushort8*)lo_dst = lv;
}

__global__ __launch_bounds__(512, 2) void gemm_dual_kernel(
    const float* __restrict__ A1a, const float* __restrict__ A2a,
    const unsigned short* __restrict__ B1ha, const unsigned short* __restrict__ B1la,
    const unsigned short* __restrict__ B2ha, const unsigned short* __restrict__ B2la,
    const float* __restrict__ biasa, float* __restrict__ Ca, int Ma, int K1a, int K2a, int nmba,
    const float* __restrict__ A1b, const float* __restrict__ A2b,
    const unsigned short* __restrict__ B1hb, const unsigned short* __restrict__ B1lb,
    const unsigned short* __restrict__ B2hb, const unsigned short* __restrict__ B2lb,
    const float* __restrict__ biasb, float* __restrict__ Cb, int Mb, int K1b, int K2b) {
    constexpr int LDAS = 40;  // bf16 elems per LDS row (+8 pad)
    __shared__ __align__(16) unsigned short Ah[128 * LDAS];
    __shared__ __align__(16) unsigned short Al[128 * LDAS];
    __shared__ __align__(16) unsigned short Bh[256 * LDAS];
    __shared__ __align__(16) unsigned short Bl[256 * LDAS];

    const float* A1; const float* A2;
    const unsigned short *B1h, *B1l, *B2h, *B2l;
    const float* bias; float* C; int M, K1, K2;
    int mb = blockIdx.x;
    if (mb < nmba) {
        A1 = A1a; A2 = A2a; B1h = B1ha; B1l = B1la; B2h = B2ha; B2l = B2la;
        bias = biasa; C = Ca; M = Ma; K1 = K1a; K2 = K2a;
    } else {
        mb -= nmba;
        A1 = A1b; A2 = A2b; B1h = B1hb; B1l = B1lb; B2h = B2hb; B2l = B2lb;
        bias = biasb; C = Cb; M = Mb; K1 = K1b; K2 = K2b;
    }
    const int Kt = K1 + K2;
    const int m0 = mb * 128;

    const int tid  = threadIdx.x;
    const int lane = tid & 63;
    const int wave = tid >> 6;
    const int wm   = (wave & 1) * 64;
    const int wn   = (wave >> 1) * 64;
    const int arow_l = tid >> 2;         // 0..127, 4 threads per A row
    const int acol   = (tid & 3) * 8;    // 8 fp32 each
    const int brow   = tid >> 1;         // 0..255, 2 threads per B row
    const int bcol   = (tid & 1) * 16;   // 16 shorts each
    const int frow = lane & 15;
    const int fk   = (lane >> 4) * 8;

    int arow = m0 + arow_l; if (arow >= M) arow = M - 1;

    floatx4 acc[4][4] = {};

    // prologue: prefetch k-tile 0 (always from the K1 operand set)
    float4 pa0, pa1;
    ushort8 ph0, ph1, pl0, pl1;
    {
        const float* ap = A1 + (size_t)arow * K1 + acol;
        pa0 = *(const float4*)(ap);
        pa1 = *(const float4*)(ap + 4);
        const unsigned short* bhp = B1h + (size_t)brow * K1 + bcol;
        const unsigned short* blp = B1l + (size_t)brow * K1 + bcol;
        ph0 = *(const ushort8*)bhp;       ph1 = *(const ushort8*)(bhp + 8);
        pl0 = *(const ushort8*)blp;       pl1 = *(const ushort8*)(blp + 8);
    }

    for (int k0 = 0; k0 < Kt; k0 += 32) {
        __syncthreads();   // prior iteration's LDS reads complete
        {
            float av[8] = {pa0.x, pa0.y, pa0.z, pa0.w, pa1.x, pa1.y, pa1.z, pa1.w};
            cvt_store8(&Ah[arow_l * LDAS + acol], &Al[arow_l * LDAS + acol], av);
            *(ushort8*)&Bh[brow * LDAS + bcol]     = ph0;
            *(ushort8*)&Bh[brow * LDAS + bcol + 8] = ph1;
            *(ushort8*)&Bl[brow * LDAS + bcol]     = pl0;
            *(ushort8*)&Bl[brow * LDAS + bcol + 8] = pl1;
        }
        __syncthreads();
        // issue next k-tile's global loads now: latency hides under MFMA
        if (k0 + 32 < Kt) {
            int kn = k0 + 32;
            const float* Ap; const unsigned short *Bhp, *Blp; int kk, lda;
            if (kn < K1) { Ap = A1; Bhp = B1h; Blp = B1l; kk = kn;      lda = K1; }
            else         { Ap = A2; Bhp = B2h; Blp = B2l; kk = kn - K1; lda = K2; }
            const float* ap = Ap + (size_t)arow * lda + kk + acol;
            pa0 = *(const float4*)(ap);
            pa1 = *(const float4*)(ap + 4);
            const unsigned short* bhp = Bhp + (size_t)brow * lda + kk + bcol;
            const unsigned short* blp = Blp + (size_t)brow * lda + kk + bcol;
            ph0 = *(const ushort8*)bhp;   ph1 = *(const ushort8*)(bhp + 8);
            pl0 = *(const ushort8*)blp;   pl1 = *(const ushort8*)(blp + 8);
        }

        short8 ahf[4], alf[4], bhf[4], blf[4];
#pragma unroll
        for (int t = 0; t < 4; t++) {
            int ar = (wm + t * 16 + frow) * LDAS + fk;
            ahf[t] = *(const short8*)&Ah[ar];
            alf[t] = *(const short8*)&Al[ar];
            int br = (wn + t * 16 + frow) * LDAS + fk;
            bhf[t] = *(const short8*)&Bh[br];
            blf[t] = *(const short8*)&Bl[br];
        }
#pragma unroll
        for (int i = 0; i < 4; i++) {
#pragma unroll
            for (int j = 0; j < 4; j++) {
                acc[i][j] = __builtin_amdgcn_mfma_f32_16x16x32_bf16(ahf[i], bhf[j], acc[i][j], 0, 0, 0);
                acc[i][j] = __builtin_amdgcn_mfma_f32_16x16x32_bf16(ahf[i], blf[j], acc[i][j], 0, 0, 0);
                acc[i][j] = __builtin_amdgcn_mfma_f32_16x16x32_bf16(alf[i], bhf[j], acc[i][j], 0, 0, 0);
            }
        }
    }

    const int colL = lane & 15;
    const int quad = lane >> 4;
#pragma unroll
    for (int j = 0; j < 4; j++) {
        int c = wn + j * 16 + colL;
        float bj = bias ? bias[c] : 0.0f;
#pragma unroll
        for (int i = 0; i < 4; i++) {
            int rbase = m0 + wm + i * 16 + quad * 4;
#pragma unroll
            for (int r = 0; r < 4; r++) {
                int row = rbase + r;
                if (row < M) {
                    float v = acc[i][j][r] + bj;
                    v = fmaxf(v, 0.0f);
                    C[(size_t)row * 256 + c] = v;
                }
            }
        }
    }
}

// ---------------- Fused attention + output projection ----------------

__global__ __launch_bounds__(256) void attn_out_kernel(
    const float* __restrict__ h, const float* __restrict__ h2,
    const float* __restrict__ q1, const float* __restrict__ q2,
    const float* __restrict__ Wout, const float* __restrict__ bout,
    float* __restrict__ out, int Bn) {
    int w = threadIdx.x >> 6, lane = threadIdx.x & 63;
    int row = blockIdx.x * 4 + w;
    __shared__ __align__(16) float cbuf[4][260];
    if (row < Bn) {
        const float4 a = *(const float4*)(h  + (size_t)row * HID + lane * 4);
        const float4 p = *(const float4*)(q1 + (size_t)row * HID + lane * 4);
        const float4 b = *(const float4*)(h2 + (size_t)row * HID + lane * 4);
        const float4 q = *(const float4*)(q2 + (size_t)row * HID + lane * 4);
        float s0 = a.x * p.x + a.y * p.y + a.z * p.z + a.w * p.w;
        float s1 = b.x * q.x + b.y * q.y + b.z * q.z + b.w * q.w;
        for (int o = 32; o > 0; o >>= 1) {
            s0 += __shfl_xor(s0, o);
            s1 += __shfl_xor(s1, o);
        }
        float m  = fmaxf(s0, s1);
        float e0 = __expf(s0 - m), e1 = __expf(s1 - m);
        float inv = 1.0f / (e0 + e1);
        float a0 = e0 * inv, a1 = e1 * inv;
        float4 cv;
        cv.x = a0 * a.x + a1 * b.x; cv.y = a0 * a.y + a1 * b.y;
        cv.z = a0 * a.z + a1 * b.z; cv.w = a0 * a.w + a1 * b.w;
        *(float4*)&cbuf[w][lane * 4] = cv;
    }
    __syncthreads();
    int t = threadIdx.x;
    if (t < 4 * NCLS) {
        int r = t / NCLS, j = t % NCLS;
        int orow = blockIdx.x * 4 + r;
        if (orow < Bn) {
            float acc = bout[j];
#pragma unroll 8
            for (int k = 0; k < HID; k++) acc += cbuf[r][k] * Wout[k * NCLS + j];
            out[(size_t)orow * NCLS + j] = acc;
        }
    }
}

}  // namespace

extern "C" void kernel_launch(void* const* d_in, const int* in_sizes, int n_in,
                              void* d_out, int out_size, void* d_ws, size_t ws_size,
                              hipStream_t stream) {
    const float* x    = (const float*)d_in[0];
    const int*   src0 = (const int*)d_in[1];
    const int*   dst0 = (const int*)d_in[2];
    const int*   src1 = (const int*)d_in[3];
    const int*   dst1 = (const int*)d_in[4];
    const float* W1l  = (const float*)d_in[5];
    const float* b1   = (const float*)d_in[6];
    const float* W1r  = (const float*)d_in[7];
    const float* W2l  = (const float*)d_in[8];
    const float* b2   = (const float*)d_in[9];
    const float* W2r  = (const float*)d_in[10];
    const float* Wout = (const float*)d_in[11];
    const float* bout = (const float*)d_in[12];
    float* out = (float*)d_out;

    // ---- workspace carve-up (256B-aligned) ----
    char* ws = (char*)d_ws;
    size_t off = 0;
    auto alloc = [&](size_t bytes) {
        void* p = ws + off;
        off = (off + bytes + 255) & ~(size_t)255;
        return p;
    };
    int* cnt0  = (int*)alloc((size_t)(N1i + Bni) * sizeof(int));  // contiguous: 1 memset
    int* cnt1  = cnt0 + N1i;
    int* rp0   = (int*)alloc((N1i + 1) * sizeof(int));
    int* rp1   = (int*)alloc((Bni + 1) * sizeof(int));
    int* bsum0 = (int*)alloc(512 * sizeof(int));
    int* bsum1 = (int*)alloc(512 * sizeof(int));
    int* es0   = (int*)alloc(E0i * sizeof(int));
    int* es1   = (int*)alloc(E1i * sizeof(int));
    unsigned short* w1l_hi = (unsigned short*)alloc(256 * FIN * sizeof(unsigned short));
    unsigned short* w1l_lo = (unsigned short*)alloc(256 * FIN * sizeof(unsigned short));
    unsigned short* w1r_hi = (unsigned short*)alloc(256 * FIN * sizeof(unsigned short));
    unsigned short* w1r_lo = (unsigned short*)alloc(256 * FIN * sizeof(unsigned short));
    unsigned short* w2l_hi = (unsigned short*)alloc(256 * HID * sizeof(unsigned short));
    unsigned short* w2l_lo = (unsigned short*)alloc(256 * HID * sizeof(unsigned short));
    unsigned short* w2r_hi = (unsigned short*)alloc(256 * HID * sizeof(unsigned short));
    unsigned short* w2r_lo = (unsigned short*)alloc(256 * HID * sizeof(unsigned short));
    float* region = (float*)alloc((size_t)N1i * FIN * sizeof(float));
    float* h      = (float*)alloc((size_t)N1i * HID * sizeof(float));
    float* hq1    = (float*)alloc((size_t)Bni * HID * sizeof(float));  // own buffer:
    // hq1 is WRITTEN concurrently with agg0 READS in the fused gemm launch,
    // so it must not alias region (the old layout aliased hq1 = region).
    float* agg0 = region;
    float* agg1 = region + (size_t)1 * Bni * HID;
    float* h2   = region + (size_t)2 * Bni * HID;
    float* h2q  = region + (size_t)3 * Bni * HID;

    const int nb0 = (N1i + 255) / 256, nb1 = (Bni + 255) / 256;
    const int nmb1g = (N1i + 127) / 128;   // 782
    const int nmbB  = (Bni + 127) / 128;   // 79

    // ---- prologue: 1 memset + 6 fused kernels ----
    hipMemsetAsync(cnt0, 0, (size_t)(N1i + Bni) * sizeof(int), stream);
    wtrans_all_kernel<<<768, 256, 0, stream>>>(W1l, W1r, W2l, W2r,
        w1l_hi, w1l_lo, w1r_hi, w1r_lo, w2l_hi, w2l_lo, w2r_hi, w2r_lo);
    hist_both_kernel<<<(E0i + E1i + 255) / 256, 256, 0, stream>>>(dst0, dst1, cnt0, cnt1);
    partial_sum_both_kernel<<<nb0 + nb1, 256, 0, stream>>>(cnt0, cnt1, bsum0, bsum1, nb0);
    scan_bsum_both_kernel<<<2, 512, 0, stream>>>(bsum0, nb0, rp0 + N1i, bsum1, nb1, rp1 + Bni);
    scan_final_both_kernel<<<nb0 + nb1, 256, 0, stream>>>(cnt0, bsum0, rp0, cnt1, bsum1, rp1, nb0);
    scatter_both_kernel<<<(E0i + E1i + 255) / 256, 256, 0, stream>>>(
        src0, dst0, src1, dst1, cnt0, cnt1, es0, es1);

    // ---- layer 1: agg + fused {h, hq1} GEMM ----
    agg_mean128_kernel<<<(N1i + 3) / 4, 256, 0, stream>>>(x, rp0, es0, agg0, N1i);
    gemm_dual_kernel<<<nmb1g + nmbB, 512, 0, stream>>>(
        agg0, x, w1l_hi, w1l_lo, w1r_hi, w1r_lo, b1, h, N1i, 128, 128, nmb1g,
        x, nullptr, w1r_hi, w1r_lo, nullptr, nullptr, nullptr, hq1, Bni, 128, 0);

    // ---- layer 2: agg + fused {h2, h2q} GEMM ----
    agg_mean256_kernel<<<(Bni + 3) / 4, 256, 0, stream>>>(h, rp1, es1, agg1, Bni);
    gemm_dual_kernel<<<nmbB + nmbB, 512, 0, stream>>>(
        agg1, h, w2l_hi, w2l_lo, w2r_hi, w2r_lo, b2, h2, Bni, 256, 256, nmbB,
        hq1, nullptr, w2r_hi, w2r_lo, nullptr, nullptr, nullptr, h2q, Bni, 256, 0);

    // ---- attention + output projection ----
    attn_out_kernel<<<(Bni + 3) / 4, 256, 0, stream>>>(h, h2, hq1, h2q, Wout, bout, out, Bni);
}

// Round 3
// 725.468 us; speedup vs baseline: 1.0279x; 1.0062x over previous
//
#include <hip/hip_runtime.h>
#include <cstddef>

// TwinSAGE: 2-layer GraphSAGE (mean aggr) + twin query path + 2-way layer
// attention + output projection.
// Round 6: single lever — gather-width/depth in the aggregation kernels.
// agg_mean128: dwordx4 per lane, TWO rows per load instruction (half-wave
// per row) -> 16 cache lines in flight per instr (was 8), all loads of a
// segment issued up-front in padded 8-batches with validity weights (no
// serial stragglers). agg_mean256: padded 8-deep issue with validity
// weights. CSR build / GEMMs / attention identical to round 5.

namespace {

constexpr int N1i  = 100000;
constexpr int Bni  = 10000;
constexpr int E0i  = 1000000;
constexpr int E1i  = 100000;
constexpr int FIN  = 128;
constexpr int HID  = 256;
constexpr int NCLS = 40;

typedef __attribute__((ext_vector_type(8))) short short8;
typedef __attribute__((ext_vector_type(8))) unsigned short ushort8;
typedef __attribute__((ext_vector_type(4))) float floatx4;

// ---------------- fused CSR build ----------------

__global__ void hist_both_kernel(const int* __restrict__ dst0, const int* __restrict__ dst1,
                                 int* __restrict__ cnt0, int* __restrict__ cnt1) {
    int i = blockIdx.x * blockDim.x + threadIdx.x;
    if (i < E0i) atomicAdd(&cnt0[dst0[i]], 1);
    else if (i < E0i + E1i) atomicAdd(&cnt1[dst1[i - E0i]], 1);
}

__global__ void partial_sum_both_kernel(const int* __restrict__ cnt0, const int* __restrict__ cnt1,
                                        int* __restrict__ bsum0, int* __restrict__ bsum1, int nb0) {
    __shared__ int s[256];
    const int* cnt; int n; int* bsum; int bi;
    if ((int)blockIdx.x < nb0) { cnt = cnt0; n = N1i; bsum = bsum0; bi = blockIdx.x; }
    else                       { cnt = cnt1; n = Bni; bsum = bsum1; bi = blockIdx.x - nb0; }
    int i = bi * 256 + threadIdx.x;
    s[threadIdx.x] = (i < n) ? cnt[i] : 0;
    __syncthreads();
    for (int o = 128; o > 0; o >>= 1) {
        if (threadIdx.x < o) s[threadIdx.x] += s[threadIdx.x + o];
        __syncthreads();
    }
    if (threadIdx.x == 0) bsum[bi] = s[0];
}

// grid = 2 blocks, 512 threads: block 0 scans bsum0, block 1 scans bsum1.
__global__ void scan_bsum_both_kernel(int* __restrict__ bsum0, int nb0, int* __restrict__ tot0,
                                      int* __restrict__ bsum1, int nb1, int* __restrict__ tot1) {
    __shared__ int s[512];
    int* bsum; int nb; int* tot;
    if (blockIdx.x == 0) { bsum = bsum0; nb = nb0; tot = tot0; }
    else                 { bsum = bsum1; nb = nb1; tot = tot1; }
    int t = threadIdx.x;
    int v = (t < nb) ? bsum[t] : 0;
    s[t] = v;
    __syncthreads();
    for (int o = 1; o < 512; o <<= 1) {
        int u = (t >= o) ? s[t - o] : 0;
        __syncthreads();
        s[t] += u;
        __syncthreads();
    }
    if (t < nb) bsum[t] = s[t] - v;   // exclusive
    if (t == 511) *tot = s[511];
}

// Writes rp[i] (exclusive prefix) AND resets cnt[i] to the same value so
// cnt doubles as the scatter cursor (replaces the old copy kernel).
__global__ void scan_final_both_kernel(int* __restrict__ cnt0, const int* __restrict__ bsum0, int* __restrict__ rp0,
                                       int* __restrict__ cnt1, const int* __restrict__ bsum1, int* __restrict__ rp1,
                                       int nb0) {
    __shared__ int s[256];
    int* cnt; const int* bsum; int* rp; int n; int bi;
    if ((int)blockIdx.x < nb0) { cnt = cnt0; bsum = bsum0; rp = rp0; n = N1i; bi = blockIdx.x; }
    else                       { cnt = cnt1; bsum = bsum1; rp = rp1; n = Bni; bi = blockIdx.x - nb0; }
    int t = threadIdx.x;
    int i = bi * 256 + t;
    int v = (i < n) ? cnt[i] : 0;
    s[t] = v;
    __syncthreads();
    for (int o = 1; o < 256; o <<= 1) {
        int u = (t >= o) ? s[t - o] : 0;
        __syncthreads();
        s[t] += u;
        __syncthreads();
    }
    if (i < n) {
        int r = bsum[bi] + s[t] - v;  // exclusive
        rp[i]  = r;
        cnt[i] = r;                   // cursor for scatter
    }
}

__global__ void scatter_both_kernel(const int* __restrict__ src0, const int* __restrict__ dst0,
                                    const int* __restrict__ src1, const int* __restrict__ dst1,
                                    int* __restrict__ cur0, int* __restrict__ cur1,
                                    int* __restrict__ es0, int* __restrict__ es1) {
    int i = blockIdx.x * blockDim.x + threadIdx.x;
    if (i < E0i) {
        int p = atomicAdd(&cur0[dst0[i]], 1);
        es0[p] = src0[i];
    } else if (i < E0i + E1i) {
        int j = i - E0i;
        int p = atomicAdd(&cur1[dst1[j]], 1);
        es1[p] = src1[j];
    }
}

// ---------------- Mean aggregation ----------------
// agg_mean128: one wave per target. Each dwordx4 load covers TWO source
// rows (lanes 0-31 -> row of even pair slot, lanes 32-63 -> odd slot):
// 16 cache lines in flight per instruction. All loads of a <=64-edge
// segment are issued in padded batches of 8 instructions (16 edges);
// out-of-range slots load a clamped duplicate row (hot line) with weight 0.

__global__ __launch_bounds__(256) void agg_mean128_kernel(
    const float* __restrict__ x, const int* __restrict__ rp,
    const int* __restrict__ es, float* __restrict__ out, int ntgt) {
    int tgt  = blockIdx.x * 4 + (threadIdx.x >> 6);
    int lane = threadIdx.x & 63;
    if (tgt >= ntgt) return;
    int b = rp[tgt], e = rp[tgt + 1];
    int d = e - b;
    int half = lane >> 5;       // which edge of the pair this half-wave loads
    int sl   = lane & 31;       // 32 lanes x 4 floats = 128 cols
    float4 acc = {0.f, 0.f, 0.f, 0.f};
    const float* xp = x + sl * 4;
    for (int base = 0; base < d; base += 64) {
        int rem = d - base; if (rem > 64) rem = 64;
        int li  = lane < rem ? lane : rem - 1;
        int idx = es[b + base + li];            // one coalesced load / 64 edges
        int rm1 = rem - 1;
        int npair = (rem + 1) >> 1;
        for (int p = 0; p < npair; p += 8) {
            int e0 = p * 2 + half;              // edge slot this half handles
            int s0 = e0      <= rm1 ? e0      : rm1;
            int s1 = e0 + 2  <= rm1 ? e0 + 2  : rm1;
            int s2 = e0 + 4  <= rm1 ? e0 + 4  : rm1;
            int s3 = e0 + 6  <= rm1 ? e0 + 6  : rm1;
            int s4 = e0 + 8  <= rm1 ? e0 + 8  : rm1;
            int s5 = e0 + 10 <= rm1 ? e0 + 10 : rm1;
            int s6 = e0 + 12 <= rm1 ? e0 + 12 : rm1;
            int s7 = e0 + 14 <= rm1 ? e0 + 14 : rm1;
            float w0 = (e0      < rem) ? 1.f : 0.f;
            float w1 = (e0 + 2  < rem) ? 1.f : 0.f;
            float w2 = (e0 + 4  < rem) ? 1.f : 0.f;
            float w3 = (e0 + 6  < rem) ? 1.f : 0.f;
            float w4 = (e0 + 8  < rem) ? 1.f : 0.f;
            float w5 = (e0 + 10 < rem) ? 1.f : 0.f;
            float w6 = (e0 + 12 < rem) ? 1.f : 0.f;
            float w7 = (e0 + 14 < rem) ? 1.f : 0.f;
            int i0 = __shfl(idx, s0), i1 = __shfl(idx, s1);
            int i2 = __shfl(idx, s2), i3 = __shfl(idx, s3);
            int i4 = __shfl(idx, s4), i5 = __shfl(idx, s5);
            int i6 = __shfl(idx, s6), i7 = __shfl(idx, s7);
            float4 v0 = *(const float4*)(xp + i0 * FIN);
            float4 v1 = *(const float4*)(xp + i1 * FIN);
            float4 v2 = *(const float4*)(xp + i2 * FIN);
            float4 v3 = *(const float4*)(xp + i3 * FIN);
            float4 v4 = *(const float4*)(xp + i4 * FIN);
            float4 v5 = *(const float4*)(xp + i5 * FIN);
            float4 v6 = *(const float4*)(xp + i6 * FIN);
            float4 v7 = *(const float4*)(xp + i7 * FIN);
            acc.x += v0.x * w0 + v1.x * w1 + v2.x * w2 + v3.x * w3
                   + v4.x * w4 + v5.x * w5 + v6.x * w6 + v7.x * w7;
            acc.y += v0.y * w0 + v1.y * w1 + v2.y * w2 + v3.y * w3
                   + v4.y * w4 + v5.y * w5 + v6.y * w6 + v7.y * w7;
            acc.z += v0.z * w0 + v1.z * w1 + v2.z * w2 + v3.z * w3
                   + v4.z * w4 + v5.z * w5 + v6.z * w6 + v7.z * w7;
            acc.w += v0.w * w0 + v1.w * w1 + v2.w * w2 + v3.w * w3
                   + v4.w * w4 + v5.w * w5 + v6.w * w6 + v7.w * w7;
        }
    }
    // combine the two half-wave partial sums (even/odd edge slots)
    acc.x += __shfl_xor(acc.x, 32);
    acc.y += __shfl_xor(acc.y, 32);
    acc.z += __shfl_xor(acc.z, 32);
    acc.w += __shfl_xor(acc.w, 32);
    if (lane < 32) {
        float inv = 1.0f / fmaxf((float)d, 1.0f);
        float4 r; r.x = acc.x * inv; r.y = acc.y * inv; r.z = acc.z * inv; r.w = acc.w * inv;
        *(float4*)(out + (size_t)tgt * FIN + sl * 4) = r;
    }
}

// agg_mean256: one wave per target, one full 1KB row per instruction
// (16 lines). Padded 8-deep issue with validity weights.
__global__ __launch_bounds__(256) void agg_mean256_kernel(
    const float* __restrict__ h, const int* __restrict__ rp,
    const int* __restrict__ es, float* __restrict__ out, int ntgt) {
    int tgt  = blockIdx.x * 4 + (threadIdx.x >> 6);
    int lane = threadIdx.x & 63;
    if (tgt >= ntgt) return;
    int b = rp[tgt], e = rp[tgt + 1];
    int d = e - b;
    float4 acc = {0.f, 0.f, 0.f, 0.f};
    const float* hp = h + lane * 4;
    for (int base = 0; base < d; base += 64) {
        int rem = d - base; if (rem > 64) rem = 64;
        int li  = lane < rem ? lane : rem - 1;
        int idx = es[b + base + li];
        int rm1 = rem - 1;
        for (int j = 0; j < rem; j += 8) {
            int s0 = j     <= rm1 ? j     : rm1;
            int s1 = j + 1 <= rm1 ? j + 1 : rm1;
            int s2 = j + 2 <= rm1 ? j + 2 : rm1;
            int s3 = j + 3 <= rm1 ? j + 3 : rm1;
            int s4 = j + 4 <= rm1 ? j + 4 : rm1;
            int s5 = j + 5 <= rm1 ? j + 5 : rm1;
            int s6 = j + 6 <= rm1 ? j + 6 : rm1;
            int s7 = j + 7 <= rm1 ? j + 7 : rm1;
            float w0 = 1.f;                      // j < rem always
            float w1 = (j + 1 < rem) ? 1.f : 0.f;
            float w2 = (j + 2 < rem) ? 1.f : 0.f;
            float w3 = (j + 3 < rem) ? 1.f : 0.f;
            float w4 = (j + 4 < rem) ? 1.f : 0.f;
            float w5 = (j + 5 < rem) ? 1.f : 0.f;
            float w6 = (j + 6 < rem) ? 1.f : 0.f;
            float w7 = (j + 7 < rem) ? 1.f : 0.f;
            int i0 = __shfl(idx, s0), i1 = __shfl(idx, s1);
            int i2 = __shfl(idx, s2), i3 = __shfl(idx, s3);
            int i4 = __shfl(idx, s4), i5 = __shfl(idx, s5);
            int i6 = __shfl(idx, s6), i7 = __shfl(idx, s7);
            float4 v0 = *(const float4*)(hp + i0 * HID);
            float4 v1 = *(const float4*)(hp + i1 * HID);
            float4 v2 = *(const float4*)(hp + i2 * HID);
            float4 v3 = *(const float4*)(hp + i3 * HID);
            float4 v4 = *(const float4*)(hp + i4 * HID);
            float4 v5 = *(const float4*)(hp + i5 * HID);
            float4 v6 = *(const float4*)(hp + i6 * HID);
            float4 v7 = *(const float4*)(hp + i7 * HID);
            acc.x += v0.x * w0 + v1.x * w1 + v2.x * w2 + v3.x * w3
                   + v4.x * w4 + v5.x * w5 + v6.x * w6 + v7.x * w7;
            acc.y += v0.y * w0 + v1.y * w1 + v2.y * w2 + v3.y * w3
                   + v4.y * w4 + v5.y * w5 + v6.y * w6 + v7.y * w7;
            acc.z += v0.z * w0 + v1.z * w1 + v2.z * w2 + v3.z * w3
                   + v4.z * w4 + v5.z * w5 + v6.z * w6 + v7.z * w7;
            acc.w += v0.w * w0 + v1.w * w1 + v2.w * w2 + v3.w * w3
                   + v4.w * w4 + v5.w * w5 + v6.w * w6 + v7.w * w7;
        }
    }
    float inv = 1.0f / fmaxf((float)d, 1.0f);
    float4 r; r.x = acc.x * inv; r.y = acc.y * inv; r.z = acc.z * inv; r.w = acc.w * inv;
    *(float4*)(out + (size_t)tgt * HID + lane * 4) = r;
}

// ---------------- weight transpose + bf16 hi/lo split (fused x4) --------

__device__ inline unsigned short bf16_rne_u(unsigned u) {
    unsigned r = u + 0x7fffu + ((u >> 16) & 1u);
    return (unsigned short)(r >> 16);
}

__global__ void wtrans_all_kernel(const float* __restrict__ W1l, const float* __restrict__ W1r,
                                  const float* __restrict__ W2l, const float* __restrict__ W2r,
                                  unsigned short* __restrict__ w1lh, unsigned short* __restrict__ w1ll,
                                  unsigned short* __restrict__ w1rh, unsigned short* __restrict__ w1rl,
                                  unsigned short* __restrict__ w2lh, unsigned short* __restrict__ w2ll,
                                  unsigned short* __restrict__ w2rh, unsigned short* __restrict__ w2rl) {
    int e = blockIdx.x * 256 + threadIdx.x;
    const float* W; unsigned short* hiT; unsigned short* loT; int K; int idx;
    if (e < 65536) {
        K = 128;
        if (e < 32768) { W = W1l; hiT = w1lh; loT = w1ll; idx = e; }
        else           { W = W1r; hiT = w1rh; loT = w1rl; idx = e - 32768; }
    } else {
        K = 256;
        int e2 = e - 65536;
        if (e2 < 65536) { W = W2l; hiT = w2lh; loT = w2ll; idx = e2; }
        else            { W = W2r; hiT = w2rh; loT = w2rl; idx = e2 - 65536; }
    }
    int k = idx >> 8, n = idx & 255;
    float f = W[idx];
    unsigned short hs = bf16_rne_u(__float_as_uint(f));
    float lo = f - __uint_as_float((unsigned)hs << 16);
    unsigned short ls = bf16_rne_u(__float_as_uint(lo));
    hiT[n * K + k] = hs;
    loT[n * K + k] = ls;
}

// ---------------- unified split-bf16 MFMA GEMM ----------------
// C[M x 256] = relu(A1@B1 + A2@B2 + bias), A fp32 row-major (stride = K),
// B pre-split/transposed bf16 hi/lo [256][K].
// 3-term split: Ahi*Bhi + Ahi*Blo + Alo*Bhi (error ~2^-17 rel).
// Block 128x256 (single N-block: A read+converted ONCE), 8 waves,
// wave = 4x4 tiles of mfma_f32_16x16x32_bf16, BK=32, reg prefetch of
// next k-tile issued before the MFMA phase. Two jobs per launch
// (blockIdx ranges) to fuse the small twin-path GEMMs.

__device__ inline void cvt_store8(unsigned short* hi_dst, unsigned short* lo_dst,
                                  const float* v) {
    ushort8 hv, lv;
#pragma unroll
    for (int i = 0; i < 8; i++) {
        float f = v[i];
        unsigned short hs = bf16_rne_u(__float_as_uint(f));
        float lo = f - __uint_as_float((unsigned)hs << 16);
        hv[i] = hs;
        lv[i] = bf16_rne_u(__float_as_uint(lo));
    }
    *(ushort8*)hi_dst = hv;
    *(ushort8*)lo_dst = lv;
}

__global__ __launch_bounds__(512, 2) void gemm_dual_kernel(
    const float* __restrict__ A1a, const float* __restrict__ A2a,
    const unsigned short* __restrict__ B1ha, const unsigned short* __restrict__ B1la,
    const unsigned short* __restrict__ B2ha, const unsigned short* __restrict__ B2la,
    const float* __restrict__ biasa, float* __restrict__ Ca, int Ma, int K1a, int K2a, int nmba,
    const float* __restrict__ A1b, const float* __restrict__ A2b,
    const unsigned short* __restrict__ B1hb, const unsigned short* __restrict__ B1lb,
    const unsigned short* __restrict__ B2hb, const unsigned short* __restrict__ B2lb,
    const float* __restrict__ biasb, float* __restrict__ Cb, int Mb, int K1b, int K2b) {
    constexpr int LDAS = 40;  // bf16 elems per LDS row (+8 pad)
    __shared__ __align__(16) unsigned short Ah[128 * LDAS];
    __shared__ __align__(16) unsigned short Al[128 * LDAS];
    __shared__ __align__(16) unsigned short Bh[256 * LDAS];
    __shared__ __align__(16) unsigned short Bl[256 * LDAS];

    const float* A1; const float* A2;
    const unsigned short *B1h, *B1l, *B2h, *B2l;
    const float* bias; float* C; int M, K1, K2;
    int mb = blockIdx.x;
    if (mb < nmba) {
        A1 = A1a; A2 = A2a; B1h = B1ha; B1l = B1la; B2h = B2ha; B2l = B2la;
        bias = biasa; C = Ca; M = Ma; K1 = K1a; K2 = K2a;
    } else {
        mb -= nmba;
        A1 = A1b; A2 = A2b; B1h = B1hb; B1l = B1lb; B2h = B2hb; B2l = B2lb;
        bias = biasb; C = Cb; M = Mb; K1 = K1b; K2 = K2b;
    }
    const int Kt = K1 + K2;
    const int m0 = mb * 128;

    const int tid  = threadIdx.x;
    const int lane = tid & 63;
    const int wave = tid >> 6;
    const int wm   = (wave & 1) * 64;
    const int wn   = (wave >> 1) * 64;
    const int arow_l = tid >> 2;         // 0..127, 4 threads per A row
    const int acol   = (tid & 3) * 8;    // 8 fp32 each
    const int brow   = tid >> 1;         // 0..255, 2 threads per B row
    const int bcol   = (tid & 1) * 16;   // 16 shorts each
    const int frow = lane & 15;
    const int fk   = (lane >> 4) * 8;

    int arow = m0 + arow_l; if (arow >= M) arow = M - 1;

    floatx4 acc[4][4] = {};

    // prologue: prefetch k-tile 0 (always from the K1 operand set)
    float4 pa0, pa1;
    ushort8 ph0, ph1, pl0, pl1;
    {
        const float* ap = A1 + (size_t)arow * K1 + acol;
        pa0 = *(const float4*)(ap);
        pa1 = *(const float4*)(ap + 4);
        const unsigned short* bhp = B1h + (size_t)brow * K1 + bcol;
        const unsigned short* blp = B1l + (size_t)brow * K1 + bcol;
        ph0 = *(const ushort8*)bhp;       ph1 = *(const ushort8*)(bhp + 8);
        pl0 = *(const ushort8*)blp;       pl1 = *(const ushort8*)(blp + 8);
    }

    for (int k0 = 0; k0 < Kt; k0 += 32) {
        __syncthreads();   // prior iteration's LDS reads complete
        {
            float av[8] = {pa0.x, pa0.y, pa0.z, pa0.w, pa1.x, pa1.y, pa1.z, pa1.w};
            cvt_store8(&Ah[arow_l * LDAS + acol], &Al[arow_l * LDAS + acol], av);
            *(ushort8*)&Bh[brow * LDAS + bcol]     = ph0;
            *(ushort8*)&Bh[brow * LDAS + bcol + 8] = ph1;
            *(ushort8*)&Bl[brow * LDAS + bcol]     = pl0;
            *(ushort8*)&Bl[brow * LDAS + bcol + 8] = pl1;
        }
        __syncthreads();
        // issue next k-tile's global loads now: latency hides under MFMA
        if (k0 + 32 < Kt) {
            int kn = k0 + 32;
            const float* Ap; const unsigned short *Bhp, *Blp; int kk, lda;
            if (kn < K1) { Ap = A1; Bhp = B1h; Blp = B1l; kk = kn;      lda = K1; }
            else         { Ap = A2; Bhp = B2h; Blp = B2l; kk = kn - K1; lda = K2; }
            const float* ap = Ap + (size_t)arow * lda + kk + acol;
            pa0 = *(const float4*)(ap);
            pa1 = *(const float4*)(ap + 4);
            const unsigned short* bhp = Bhp + (size_t)brow * lda + kk + bcol;
            const unsigned short* blp = Blp + (size_t)brow * lda + kk + bcol;
            ph0 = *(const ushort8*)bhp;   ph1 = *(const ushort8*)(bhp + 8);
            pl0 = *(const ushort8*)blp;   pl1 = *(const ushort8*)(blp + 8);
        }

        short8 ahf[4], alf[4], bhf[4], blf[4];
#pragma unroll
        for (int t = 0; t < 4; t++) {
            int ar = (wm + t * 16 + frow) * LDAS + fk;
            ahf[t] = *(const short8*)&Ah[ar];
            alf[t] = *(const short8*)&Al[ar];
            int br = (wn + t * 16 + frow) * LDAS + fk;
            bhf[t] = *(const short8*)&Bh[br];
            blf[t] = *(const short8*)&Bl[br];
        }
#pragma unroll
        for (int i = 0; i < 4; i++) {
#pragma unroll
            for (int j = 0; j < 4; j++) {
                acc[i][j] = __builtin_amdgcn_mfma_f32_16x16x32_bf16(ahf[i], bhf[j], acc[i][j], 0, 0, 0);
                acc[i][j] = __builtin_amdgcn_mfma_f32_16x16x32_bf16(ahf[i], blf[j], acc[i][j], 0, 0, 0);
                acc[i][j] = __builtin_amdgcn_mfma_f32_16x16x32_bf16(alf[i], bhf[j], acc[i][j], 0, 0, 0);
            }
        }
    }

    const int colL = lane & 15;
    const int quad = lane >> 4;
#pragma unroll
    for (int j = 0; j < 4; j++) {
        int c = wn + j * 16 + colL;
        float bj = bias ? bias[c] : 0.0f;
#pragma unroll
        for (int i = 0; i < 4; i++) {
            int rbase = m0 + wm + i * 16 + quad * 4;
#pragma unroll
            for (int r = 0; r < 4; r++) {
                int row = rbase + r;
                if (row < M) {
                    float v = acc[i][j][r] + bj;
                    v = fmaxf(v, 0.0f);
                    C[(size_t)row * 256 + c] = v;
                }
            }
        }
    }
}

// ---------------- Fused attention + output projection ----------------

__global__ __launch_bounds__(256) void attn_out_kernel(
    const float* __restrict__ h, const float* __restrict__ h2,
    const float* __restrict__ q1, const float* __restrict__ q2,
    const float* __restrict__ Wout, const float* __restrict__ bout,
    float* __restrict__ out, int Bn) {
    int w = threadIdx.x >> 6, lane = threadIdx.x & 63;
    int row = blockIdx.x * 4 + w;
    __shared__ __align__(16) float cbuf[4][260];
    if (row < Bn) {
        const float4 a = *(const float4*)(h  + (size_t)row * HID + lane * 4);
        const float4 p = *(const float4*)(q1 + (size_t)row * HID + lane * 4);
        const float4 b = *(const float4*)(h2 + (size_t)row * HID + lane * 4);
        const float4 q = *(const float4*)(q2 + (size_t)row * HID + lane * 4);
        float s0 = a.x * p.x + a.y * p.y + a.z * p.z + a.w * p.w;
        float s1 = b.x * q.x + b.y * q.y + b.z * q.z + b.w * q.w;
        for (int o = 32; o > 0; o >>= 1) {
            s0 += __shfl_xor(s0, o);
            s1 += __shfl_xor(s1, o);
        }
        float m  = fmaxf(s0, s1);
        float e0 = __expf(s0 - m), e1 = __expf(s1 - m);
        float inv = 1.0f / (e0 + e1);
        float a0 = e0 * inv, a1 = e1 * inv;
        float4 cv;
        cv.x = a0 * a.x + a1 * b.x; cv.y = a0 * a.y + a1 * b.y;
        cv.z = a0 * a.z + a1 * b.z; cv.w = a0 * a.w + a1 * b.w;
        *(float4*)&cbuf[w][lane * 4] = cv;
    }
    __syncthreads();
    int t = threadIdx.x;
    if (t < 4 * NCLS) {
        int r = t / NCLS, j = t % NCLS;
        int orow = blockIdx.x * 4 + r;
        if (orow < Bn) {
            float acc = bout[j];
#pragma unroll 8
            for (int k = 0; k < HID; k++) acc += cbuf[r][k] * Wout[k * NCLS + j];
            out[(size_t)orow * NCLS + j] = acc;
        }
    }
}

}  // namespace

extern "C" void kernel_launch(void* const* d_in, const int* in_sizes, int n_in,
                              void* d_out, int out_size, void* d_ws, size_t ws_size,
                              hipStream_t stream) {
    const float* x    = (const float*)d_in[0];
    const int*   src0 = (const int*)d_in[1];
    const int*   dst0 = (const int*)d_in[2];
    const int*   src1 = (const int*)d_in[3];
    const int*   dst1 = (const int*)d_in[4];
    const float* W1l  = (const float*)d_in[5];
    const float* b1   = (const float*)d_in[6];
    const float* W1r  = (const float*)d_in[7];
    const float* W2l  = (const float*)d_in[8];
    const float* b2   = (const float*)d_in[9];
    const float* W2r  = (const float*)d_in[10];
    const float* Wout = (const float*)d_in[11];
    const float* bout = (const float*)d_in[12];
    float* out = (float*)d_out;

    // ---- workspace carve-up (256B-aligned) ----
    char* ws = (char*)d_ws;
    size_t off = 0;
    auto alloc = [&](size_t bytes) {
        void* p = ws + off;
        off = (off + bytes + 255) & ~(size_t)255;
        return p;
    };
    int* cnt0  = (int*)alloc((size_t)(N1i + Bni) * sizeof(int));  // contiguous: 1 memset
    int* cnt1  = cnt0 + N1i;
    int* rp0   = (int*)alloc((N1i + 1) * sizeof(int));
    int* rp1   = (int*)alloc((Bni + 1) * sizeof(int));
    int* bsum0 = (int*)alloc(512 * sizeof(int));
    int* bsum1 = (int*)alloc(512 * sizeof(int));
    int* es0   = (int*)alloc(E0i * sizeof(int));
    int* es1   = (int*)alloc(E1i * sizeof(int));
    unsigned short* w1l_hi = (unsigned short*)alloc(256 * FIN * sizeof(unsigned short));
    unsigned short* w1l_lo = (unsigned short*)alloc(256 * FIN * sizeof(unsigned short));
    unsigned short* w1r_hi = (unsigned short*)alloc(256 * FIN * sizeof(unsigned short));
    unsigned short* w1r_lo = (unsigned short*)alloc(256 * FIN * sizeof(unsigned short));
    unsigned short* w2l_hi = (unsigned short*)alloc(256 * HID * sizeof(unsigned short));
    unsigned short* w2l_lo = (unsigned short*)alloc(256 * HID * sizeof(unsigned short));
    unsigned short* w2r_hi = (unsigned short*)alloc(256 * HID * sizeof(unsigned short));
    unsigned short* w2r_lo = (unsigned short*)alloc(256 * HID * sizeof(unsigned short));
    float* region = (float*)alloc((size_t)N1i * FIN * sizeof(float));
    float* h      = (float*)alloc((size_t)N1i * HID * sizeof(float));
    float* hq1    = (float*)alloc((size_t)Bni * HID * sizeof(float));  // own buffer:
    // hq1 is WRITTEN concurrently with agg0 READS in the fused gemm launch,
    // so it must not alias region.
    float* agg0 = region;
    float* agg1 = region + (size_t)1 * Bni * HID;
    float* h2   = region + (size_t)2 * Bni * HID;
    float* h2q  = region + (size_t)3 * Bni * HID;

    const int nb0 = (N1i + 255) / 256, nb1 = (Bni + 255) / 256;
    const int nmb1g = (N1i + 127) / 128;   // 782
    const int nmbB  = (Bni + 127) / 128;   // 79

    // ---- prologue: 1 memset + 6 fused kernels ----
    hipMemsetAsync(cnt0, 0, (size_t)(N1i + Bni) * sizeof(int), stream);
    wtrans_all_kernel<<<768, 256, 0, stream>>>(W1l, W1r, W2l, W2r,
        w1l_hi, w1l_lo, w1r_hi, w1r_lo, w2l_hi, w2l_lo, w2r_hi, w2r_lo);
    hist_both_kernel<<<(E0i + E1i + 255) / 256, 256, 0, stream>>>(dst0, dst1, cnt0, cnt1);
    partial_sum_both_kernel<<<nb0 + nb1, 256, 0, stream>>>(cnt0, cnt1, bsum0, bsum1, nb0);
    scan_bsum_both_kernel<<<2, 512, 0, stream>>>(bsum0, nb0, rp0 + N1i, bsum1, nb1, rp1 + Bni);
    scan_final_both_kernel<<<nb0 + nb1, 256, 0, stream>>>(cnt0, bsum0, rp0, cnt1, bsum1, rp1, nb0);
    scatter_both_kernel<<<(E0i + E1i + 255) / 256, 256, 0, stream>>>(
        src0, dst0, src1, dst1, cnt0, cnt1, es0, es1);

    // ---- layer 1: agg + fused {h, hq1} GEMM ----
    agg_mean128_kernel<<<(N1i + 3) / 4, 256, 0, stream>>>(x, rp0, es0, agg0, N1i);
    gemm_dual_kernel<<<nmb1g + nmbB, 512, 0, stream>>>(
        agg0, x, w1l_hi, w1l_lo, w1r_hi, w1r_lo, b1, h, N1i, 128, 128, nmb1g,
        x, nullptr, w1r_hi, w1r_lo, nullptr, nullptr, nullptr, hq1, Bni, 128, 0);

    // ---- layer 2: agg + fused {h2, h2q} GEMM ----
    agg_mean256_kernel<<<(Bni + 3) / 4, 256, 0, stream>>>(h, rp1, es1, agg1, Bni);
    gemm_dual_kernel<<<nmbB + nmbB, 512, 0, stream>>>(
        agg1, h, w2l_hi, w2l_lo, w2r_hi, w2r_lo, b2, h2, Bni, 256, 256, nmbB,
        hq1, nullptr, w2r_hi, w2r_lo, nullptr, nullptr, nullptr, h2q, Bni, 256, 0);

    // ---- attention + output projection ----
    attn_out_kernel<<<(Bni + 3) / 4, 256, 0, stream>>>(h, h2, hq1, h2q, Wout, bout, out, Bni);
}